// Round 7
// baseline (217.876 us; speedup 1.0000x reference)
//
#include <hip/hip_runtime.h>
#include <hip/hip_bf16.h>

#define NN 16384
#define TT 4
#define HH 64
#define NT (NN * TT)
#define CAP 128  // bucket capacity per node per edge-set; Poisson(16) => P(deg>=128) ~ 0
#define NEG_SLOPE 0.2f
#define LN_EPS 1e-5f

typedef __attribute__((ext_vector_type(8))) short short8;   // 8 bf16 (4 VGPRs)
typedef __attribute__((ext_vector_type(4))) float f32x4;    // MFMA accumulator

__device__ __forceinline__ float bf2f(unsigned short u) {
    return __uint_as_float((unsigned)u << 16);
}
// f32 -> bf16 RNE, layout-independent
__device__ __forceinline__ unsigned short f2bf(float f) {
    unsigned u = __float_as_uint(f);
    return (unsigned short)((u + 0x7FFF + ((u >> 16) & 1)) >> 16);
}

// ---------------- dispatch 1: zero counters + pack W fragments ----------------
// blocks 0..127: zero cnt2 (2*NN ints). blocks 128..135: pack the four 64x64 f32
// W matrices into bf16 MFMA B-fragment layout:
// wpack[mat*512 + (c*2+ks)*64 + lane] = short8 of W[k=ks*32+quad*8+j][n=c*16+m].

__global__ __launch_bounds__(256) void prep_kernel(
    const float* __restrict__ W0s_, const float* __restrict__ W0f_,
    const float* __restrict__ W1s_, const float* __restrict__ W1f_,
    short8* __restrict__ wpack, int* __restrict__ cnt2) {
    const int b = blockIdx.x;
    if (b < 128) {
        cnt2[b * 256 + threadIdx.x] = 0;
        return;
    }
    int id = (b - 128) * 256 + threadIdx.x;   // [0, 2048)
    int mat = id >> 9;
    int slot = id & 511;
    int lane = slot & 63;
    int cks = slot >> 6;
    int c = cks >> 1, ks = cks & 1;
    int m = lane & 15, quad = lane >> 4;
    const float* W = (mat == 0) ? W0s_ : (mat == 1) ? W0f_ : (mat == 2) ? W1s_ : W1f_;
    short8 v;
#pragma unroll
    for (int j = 0; j < 8; j++) {
        int k = ks * 32 + quad * 8 + j;
        int n = c * 16 + m;
        v[j] = (short)f2bf(W[k * 64 + n]);
    }
    wpack[id] = v;
}

// ------- full-width dual transform body (layer 0) -------
// v_mfma_f32_16x16x32_bf16. A-frag: A[m=lane&15][k=quad*8+j]. B-frag (KxN):
// B[k=quad*8+j][n=lane&15]. C/D: col=lane&15, row=quad*4+reg.
// Wave = 32 rows (2 row-tiles); block = 4 waves = 128 rows; 512 blocks = NT rows.
// Stores esc = exp(leakyrelu(score)) so the aggregate never runs exp (softmax is
// single-pass without max subtraction; logits are O(+-8)).

__device__ __forceinline__ void transform_body(
    int bid, const float4* __restrict__ x4,
    const short8* __restrict__ wp_s, const float* __restrict__ as_,
    const short8* __restrict__ wp_f, const float* __restrict__ af,
    unsigned short* __restrict__ h_s, float* __restrict__ esc_s,
    unsigned short* __restrict__ h_f, float* __restrict__ esc_f) {
    const int lane = threadIdx.x & 63;
    const int wv = threadIdx.x >> 6;
    const int m = lane & 15;
    const int quad = lane >> 4;

    short8 Bs[4][2], Bf[4][2];
#pragma unroll
    for (int c = 0; c < 4; c++) {
#pragma unroll
        for (int ks = 0; ks < 2; ks++) {
            Bs[c][ks] = wp_s[(c * 2 + ks) * 64 + lane];
            Bf[c][ks] = wp_f[(c * 2 + ks) * 64 + lane];
        }
    }
    float a_s[4], a_f[4];
#pragma unroll
    for (int c = 0; c < 4; c++) { a_s[c] = as_[c * 16 + m]; a_f[c] = af[c * 16 + m]; }

    const int rowbase = bid * 128 + wv * 32;
#pragma unroll
    for (int rt = 0; rt < 2; rt++) {
        const int row0 = rowbase + rt * 16;
        const long xbase = (long)(row0 + m) * 16 + quad * 2;
        float4 xa = x4[xbase];
        float4 xb = x4[xbase + 1];
        float4 xc = x4[xbase + 8];
        float4 xd = x4[xbase + 9];
        short8 A0, A1;
        A0[0] = (short)f2bf(xa.x); A0[1] = (short)f2bf(xa.y);
        A0[2] = (short)f2bf(xa.z); A0[3] = (short)f2bf(xa.w);
        A0[4] = (short)f2bf(xb.x); A0[5] = (short)f2bf(xb.y);
        A0[6] = (short)f2bf(xb.z); A0[7] = (short)f2bf(xb.w);
        A1[0] = (short)f2bf(xc.x); A1[1] = (short)f2bf(xc.y);
        A1[2] = (short)f2bf(xc.z); A1[3] = (short)f2bf(xc.w);
        A1[4] = (short)f2bf(xd.x); A1[5] = (short)f2bf(xd.y);
        A1[6] = (short)f2bf(xd.z); A1[7] = (short)f2bf(xd.w);

        f32x4 accs[4], accf[4];
#pragma unroll
        for (int c = 0; c < 4; c++) {
            accs[c] = (f32x4){0.f, 0.f, 0.f, 0.f};
            accf[c] = (f32x4){0.f, 0.f, 0.f, 0.f};
        }
#pragma unroll
        for (int c = 0; c < 4; c++) {
            accs[c] = __builtin_amdgcn_mfma_f32_16x16x32_bf16(A0, Bs[c][0], accs[c], 0, 0, 0);
            accs[c] = __builtin_amdgcn_mfma_f32_16x16x32_bf16(A1, Bs[c][1], accs[c], 0, 0, 0);
            accf[c] = __builtin_amdgcn_mfma_f32_16x16x32_bf16(A0, Bf[c][0], accf[c], 0, 0, 0);
            accf[c] = __builtin_amdgcn_mfma_f32_16x16x32_bf16(A1, Bf[c][1], accf[c], 0, 0, 0);
        }
#pragma unroll
        for (int reg = 0; reg < 4; reg++) {
            const int row = row0 + quad * 4 + reg;
            float ps = 0.f, pf = 0.f;
#pragma unroll
            for (int c = 0; c < 4; c++) {
                h_s[(long)row * 64 + c * 16 + m] = f2bf(accs[c][reg]);
                h_f[(long)row * 64 + c * 16 + m] = f2bf(accf[c][reg]);
                ps = fmaf(accs[c][reg], a_s[c], ps);
                pf = fmaf(accf[c][reg], a_f[c], pf);
            }
#pragma unroll
            for (int off = 1; off < 16; off <<= 1) {
                ps += __shfl_xor(ps, off, 64);
                pf += __shfl_xor(pf, off, 64);
            }
            if (m == 0) {
                float ls = (ps > 0.f) ? ps : NEG_SLOPE * ps;  // LeakyReLU folded in
                float lf = (pf > 0.f) ? pf : NEG_SLOPE * pf;
                esc_s[row] = __expf(ls);  // pre-exponentiated score
                esc_f[row] = __expf(lf);
            }
        }
    }
}

// ---------------- dispatch 2: scatter || transform0 (independent work) ----------------

__global__ __launch_bounds__(256) void st0_kernel(
    const int* __restrict__ ei_s, const int* __restrict__ ei_f, int E,
    int* __restrict__ cnt2, int* __restrict__ col2,
    const float4* __restrict__ pred, const short8* __restrict__ wpack,
    const float* __restrict__ a0s, const float* __restrict__ a0f,
    unsigned short* __restrict__ h_s, float* __restrict__ esc_s,
    unsigned short* __restrict__ h_f, float* __restrict__ esc_f) {
    if (blockIdx.x < 512) {
        transform_body(blockIdx.x, pred, wpack, a0s, wpack + 512, a0f,
                       h_s, esc_s, h_f, esc_f);
        return;
    }
    int e = (blockIdx.x - 512) * 256 + threadIdx.x;
    if (e >= 2 * E) return;
    if (e < E) {
        int d = ei_s[E + e];
        int pos = atomicAdd(&cnt2[d], 1);
        if (pos < CAP) col2[d * CAP + pos] = ei_s[e];
    } else {
        e -= E;
        int d = ei_f[E + e];
        int pos = atomicAdd(&cnt2[NN + d], 1);
        if (pos < CAP) col2[(long)NN * CAP + d * CAP + pos] = ei_f[e];
    }
}

// ---------------- paired aggregate (2 nodes per wave) ----------------
// Wave = 2 nodes = 4 independent edge lists (2 nodes x 2 sets). Index vectors
// preloaded with one coalesced 64-wide load per list; per-edge indices broadcast
// via v_readlane (SGPR address math). Gathers issued in batches of 4 PER LIST,
// all four lists interleaved -> one list's accumulate drain overlaps the other
// lists' fetches (deeper effective MLP than one-node batch-8). lane: t=lane>>4,
// channels 4*(lane&15)..+3. Returns both post-LN float4 rows.

__device__ __forceinline__ void aggregate_pair(
    int nA, int nB, int lane, int t,
    const float4* __restrict__ x4,
    const ushort4* __restrict__ hs4, const float* __restrict__ escs,
    const int* __restrict__ cnts, const int* __restrict__ cols,
    const ushort4* __restrict__ hf4, const float* __restrict__ escf,
    const int* __restrict__ cntf, const int* __restrict__ colf,
    float4 gv, float4 bv, float4& oA, float4& oB) {
    int cSA = cnts[nA]; if (cSA > CAP) cSA = CAP;
    int cFA = cntf[nA]; if (cFA > CAP) cFA = CAP;
    int cSB = cnts[nB]; if (cSB > CAP) cSB = CAP;
    int cFB = cntf[nB]; if (cFB > CAP) cFB = CAP;
    cSA = __builtin_amdgcn_readfirstlane(cSA);
    cFA = __builtin_amdgcn_readfirstlane(cFA);
    cSB = __builtin_amdgcn_readfirstlane(cSB);
    cFB = __builtin_amdgcn_readfirstlane(cFB);
    const int* colSA = cols + (long)nA * CAP;
    const int* colFA = colf + (long)nA * CAP;
    const int* colSB = cols + (long)nB * CAP;
    const int* colFB = colf + (long)nB * CAP;

    int idxSA = colSA[lane]; if (lane >= cSA) idxSA = 0;
    int idxFA = colFA[lane]; if (lane >= cFA) idxFA = 0;
    int idxSB = colSB[lane]; if (lane >= cSB) idxSB = 0;
    int idxFB = colFB[lane]; if (lane >= cFB) idxFB = 0;

    const int cSA64 = cSA < 64 ? cSA : 64;
    const int cFA64 = cFA < 64 ? cFA : 64;
    const int cSB64 = cSB < 64 ? cSB : 64;
    const int cFB64 = cFB < 64 ? cFB : 64;

    float dSA = 0.f, sxA = 0.f, syA = 0.f, szA = 0.f, swA = 0.f;
    float dFA = 0.f, fxA = 0.f, fyA = 0.f, fzA = 0.f, fwA = 0.f;
    float dSB = 0.f, sxB = 0.f, syB = 0.f, szB = 0.f, swB = 0.f;
    float dFB = 0.f, fxB = 0.f, fyB = 0.f, fzB = 0.f, fwB = 0.f;

    const int nbSA = (cSA64 + 3) >> 2;
    const int nbFA = (cFA64 + 3) >> 2;
    const int nbSB = (cSB64 + 3) >> 2;
    const int nbFB = (cFB64 + 3) >> 2;
    int nb = nbSA;
    if (nbFA > nb) nb = nbFA;
    if (nbSB > nb) nb = nbSB;
    if (nbFB > nb) nb = nbFB;

    for (int it = 0; it < nb; ++it) {
        const int j = it << 2;
        const bool doSA = it < nbSA, doFA = it < nbFA;
        const bool doSB = it < nbSB, doFB = it < nbFB;
        int sSA[4], sFA[4], sSB[4], sFB[4];
        float eSA[4], eFA[4], eSB[4], eFB[4];
        ushort4 hSA[4], hFA[4], hSB[4], hFB[4];

        // issue ALL four lists' gathers before consuming any
        if (doSA) {
#pragma unroll
            for (int u = 0; u < 4; u++) sSA[u] = __builtin_amdgcn_readlane(idxSA, j + u);
#pragma unroll
            for (int u = 0; u < 4; u++) hSA[u] = hs4[sSA[u] * 64 + lane];
#pragma unroll
            for (int u = 0; u < 4; u++) eSA[u] = escs[sSA[u] * 4 + t];
        }
        if (doFA) {
#pragma unroll
            for (int u = 0; u < 4; u++) sFA[u] = __builtin_amdgcn_readlane(idxFA, j + u);
#pragma unroll
            for (int u = 0; u < 4; u++) hFA[u] = hf4[sFA[u] * 64 + lane];
#pragma unroll
            for (int u = 0; u < 4; u++) eFA[u] = escf[sFA[u] * 4 + t];
        }
        if (doSB) {
#pragma unroll
            for (int u = 0; u < 4; u++) sSB[u] = __builtin_amdgcn_readlane(idxSB, j + u);
#pragma unroll
            for (int u = 0; u < 4; u++) hSB[u] = hs4[sSB[u] * 64 + lane];
#pragma unroll
            for (int u = 0; u < 4; u++) eSB[u] = escs[sSB[u] * 4 + t];
        }
        if (doFB) {
#pragma unroll
            for (int u = 0; u < 4; u++) sFB[u] = __builtin_amdgcn_readlane(idxFB, j + u);
#pragma unroll
            for (int u = 0; u < 4; u++) hFB[u] = hf4[sFB[u] * 64 + lane];
#pragma unroll
            for (int u = 0; u < 4; u++) eFB[u] = escf[sFB[u] * 4 + t];
        }
        if (doSA) {
#pragma unroll
            for (int u = 0; u < 4; u++) {
                float e = (j + u < cSA64) ? eSA[u] : 0.f;
                dSA += e;
                sxA = fmaf(e, bf2f(hSA[u].x), sxA);
                syA = fmaf(e, bf2f(hSA[u].y), syA);
                szA = fmaf(e, bf2f(hSA[u].z), szA);
                swA = fmaf(e, bf2f(hSA[u].w), swA);
            }
        }
        if (doFA) {
#pragma unroll
            for (int u = 0; u < 4; u++) {
                float e = (j + u < cFA64) ? eFA[u] : 0.f;
                dFA += e;
                fxA = fmaf(e, bf2f(hFA[u].x), fxA);
                fyA = fmaf(e, bf2f(hFA[u].y), fyA);
                fzA = fmaf(e, bf2f(hFA[u].z), fzA);
                fwA = fmaf(e, bf2f(hFA[u].w), fwA);
            }
        }
        if (doSB) {
#pragma unroll
            for (int u = 0; u < 4; u++) {
                float e = (j + u < cSB64) ? eSB[u] : 0.f;
                dSB += e;
                sxB = fmaf(e, bf2f(hSB[u].x), sxB);
                syB = fmaf(e, bf2f(hSB[u].y), syB);
                szB = fmaf(e, bf2f(hSB[u].z), szB);
                swB = fmaf(e, bf2f(hSB[u].w), swB);
            }
        }
        if (doFB) {
#pragma unroll
            for (int u = 0; u < 4; u++) {
                float e = (j + u < cFB64) ? eFB[u] : 0.f;
                dFB += e;
                fxB = fmaf(e, bf2f(hFB[u].x), fxB);
                fyB = fmaf(e, bf2f(hFB[u].y), fyB);
                fzB = fmaf(e, bf2f(hFB[u].z), fzB);
                fwB = fmaf(e, bf2f(hFB[u].w), fwB);
            }
        }
    }

    // tails beyond 64 edges (statistically unreachable; correctness guard)
    for (int j2 = 64; j2 < cSA; ++j2) {
        int s0 = colSA[j2];
        float e0 = escs[s0 * 4 + t];
        ushort4 h0 = hs4[(long)s0 * 64 + lane];
        dSA += e0;
        sxA = fmaf(e0, bf2f(h0.x), sxA); syA = fmaf(e0, bf2f(h0.y), syA);
        szA = fmaf(e0, bf2f(h0.z), szA); swA = fmaf(e0, bf2f(h0.w), swA);
    }
    for (int j2 = 64; j2 < cFA; ++j2) {
        int s0 = colFA[j2];
        float e0 = escf[s0 * 4 + t];
        ushort4 h0 = hf4[(long)s0 * 64 + lane];
        dFA += e0;
        fxA = fmaf(e0, bf2f(h0.x), fxA); fyA = fmaf(e0, bf2f(h0.y), fyA);
        fzA = fmaf(e0, bf2f(h0.z), fzA); fwA = fmaf(e0, bf2f(h0.w), fwA);
    }
    for (int j2 = 64; j2 < cSB; ++j2) {
        int s0 = colSB[j2];
        float e0 = escs[s0 * 4 + t];
        ushort4 h0 = hs4[(long)s0 * 64 + lane];
        dSB += e0;
        sxB = fmaf(e0, bf2f(h0.x), sxB); syB = fmaf(e0, bf2f(h0.y), syB);
        szB = fmaf(e0, bf2f(h0.z), szB); swB = fmaf(e0, bf2f(h0.w), swB);
    }
    for (int j2 = 64; j2 < cFB; ++j2) {
        int s0 = colFB[j2];
        float e0 = escf[s0 * 4 + t];
        ushort4 h0 = hf4[(long)s0 * 64 + lane];
        dFB += e0;
        fxB = fmaf(e0, bf2f(h0.x), fxB); fyB = fmaf(e0, bf2f(h0.y), fyB);
        fzB = fmaf(e0, bf2f(h0.z), fzB); fwB = fmaf(e0, bf2f(h0.w), fwB);
    }

    // normalize, residual, LN (node A then node B; chains independent)
    float msxA = 0.f, msyA = 0.f, mszA = 0.f, mswA = 0.f;
    if (dSA > 0.f) { float r = 1.f / dSA; msxA = sxA * r; msyA = syA * r; mszA = szA * r; mswA = swA * r; }
    float mfxA = 0.f, mfyA = 0.f, mfzA = 0.f, mfwA = 0.f;
    if (dFA > 0.f) { float r = 1.f / dFA; mfxA = fxA * r; mfyA = fyA * r; mfzA = fzA * r; mfwA = fwA * r; }
    float msxB = 0.f, msyB = 0.f, mszB = 0.f, mswB = 0.f;
    if (dSB > 0.f) { float r = 1.f / dSB; msxB = sxB * r; msyB = syB * r; mszB = szB * r; mswB = swB * r; }
    float mfxB = 0.f, mfyB = 0.f, mfzB = 0.f, mfwB = 0.f;
    if (dFB > 0.f) { float r = 1.f / dFB; mfxB = fxB * r; mfyB = fyB * r; mfzB = fzB * r; mfwB = fwB * r; }

    float4 xvA = x4[(long)nA * 64 + lane];
    float4 xvB = x4[(long)nB * 64 + lane];
    float a0 = xvA.x + 0.5f * (msxA + mfxA);
    float a1 = xvA.y + 0.5f * (msyA + mfyA);
    float a2 = xvA.z + 0.5f * (mszA + mfzA);
    float a3 = xvA.w + 0.5f * (mswA + mfwA);
    float b0 = xvB.x + 0.5f * (msxB + mfxB);
    float b1 = xvB.y + 0.5f * (msyB + mfyB);
    float b2 = xvB.z + 0.5f * (mszB + mfzB);
    float b3 = xvB.w + 0.5f * (mswB + mfwB);

    float sumA = (a0 + a1) + (a2 + a3);
    float sumB = (b0 + b1) + (b2 + b3);
#pragma unroll
    for (int off = 1; off < 16; off <<= 1) {
        sumA += __shfl_xor(sumA, off, 64);
        sumB += __shfl_xor(sumB, off, 64);
    }
    float muA = sumA * (1.f / 64.f), muB = sumB * (1.f / 64.f);
    float dA0 = a0 - muA, dA1 = a1 - muA, dA2 = a2 - muA, dA3 = a3 - muA;
    float dB0 = b0 - muB, dB1 = b1 - muB, dB2 = b2 - muB, dB3 = b3 - muB;
    float varA = (dA0 * dA0 + dA1 * dA1) + (dA2 * dA2 + dA3 * dA3);
    float varB = (dB0 * dB0 + dB1 * dB1) + (dB2 * dB2 + dB3 * dB3);
#pragma unroll
    for (int off = 1; off < 16; off <<= 1) {
        varA += __shfl_xor(varA, off, 64);
        varB += __shfl_xor(varB, off, 64);
    }
    float invA = rsqrtf(varA * (1.f / 64.f) + LN_EPS);
    float invB = rsqrtf(varB * (1.f / 64.f) + LN_EPS);
    oA.x = dA0 * invA * gv.x + bv.x; oA.y = dA1 * invA * gv.y + bv.y;
    oA.z = dA2 * invA * gv.z + bv.z; oA.w = dA3 * invA * gv.w + bv.w;
    oB.x = dB0 * invB * gv.x + bv.x; oB.y = dB1 * invB * gv.y + bv.y;
    oB.z = dB2 * invB * gv.z + bv.z; oB.w = dB3 * invB * gv.w + bv.w;
}

// ---------------- dispatch 3: aggregate0 + transform1 fused ----------------
// Phase A: paired aggregate (wave = 2 nodes, block = 8 nodes = 32 rows), writes
// x_mid (f32 residual) and LN output as bf16 into padded LDS (row stride 144B:
// bank = 4*((9m+quad)%8) -> 2-way, free; the r6 unpadded layout was 16-way).
// Phase B: 32 rows = two MFMA row-tiles. Wave wv computes c-chunk wv for both
// tiles and both sets (8 MFMAs). Score partials summed via LDS.

__global__ __launch_bounds__(256) void a0t1_kernel(
    const float4* __restrict__ pred,
    const ushort4* __restrict__ hs4, const float* __restrict__ escs,
    const int* __restrict__ cnts, const int* __restrict__ cols,
    const ushort4* __restrict__ hf4, const float* __restrict__ escf,
    const int* __restrict__ cntf, const int* __restrict__ colf,
    const float4* __restrict__ g4, const float4* __restrict__ b4,
    float4* __restrict__ xmid4,
    const short8* __restrict__ wp1s, const short8* __restrict__ wp1f,
    const float* __restrict__ a1s, const float* __restrict__ a1f,
    unsigned short* __restrict__ h1_s, float* __restrict__ esc1_s,
    unsigned short* __restrict__ h1_f, float* __restrict__ esc1_f) {
    __shared__ __align__(16) ushort4 xb4[32][18];  // padded: 18 ushort4 = 144B/row
    __shared__ float psumS[4][2][16];
    __shared__ float psumF[4][2][16];
    const int wv = threadIdx.x >> 6;
    const int lane = threadIdx.x & 63;
    const int t = lane >> 4;
    const int ci = lane & 15;
    const int n0 = blockIdx.x * 8;
    const int nA = n0 + wv * 2, nB = nA + 1;

    // ---- phase A: layer-0 aggregate + residual + LN (2 nodes/wave) ----
    float4 oA, oB;
    aggregate_pair(nA, nB, lane, t, pred, hs4, escs, cnts, cols,
                   hf4, escf, cntf, colf, g4[ci], b4[ci], oA, oB);
    xmid4[(long)nA * 64 + lane] = oA;  // f32 for layer-1 residual
    xmid4[(long)nB * 64 + lane] = oB;
    ushort4 xuA, xuB;
    xuA.x = f2bf(oA.x); xuA.y = f2bf(oA.y); xuA.z = f2bf(oA.z); xuA.w = f2bf(oA.w);
    xuB.x = f2bf(oB.x); xuB.y = f2bf(oB.y); xuB.z = f2bf(oB.z); xuB.w = f2bf(oB.w);
    xb4[wv * 8 + t][ci] = xuA;       // local row of nA = wv*8 + t
    xb4[wv * 8 + 4 + t][ci] = xuB;   // local row of nB = wv*8 + 4 + t
    __syncthreads();

    // ---- phase B: layer-1 transform for the block's 32 rows; c-chunk = wv ----
    const int m = lane & 15;
    const int quad = lane >> 4;
    const short8* xbs8 = (const short8*)xb4;     // row stride = 9 short8
    short8 Bs0 = wp1s[(wv * 2 + 0) * 64 + lane];
    short8 Bs1 = wp1s[(wv * 2 + 1) * 64 + lane];
    short8 Bf0 = wp1f[(wv * 2 + 0) * 64 + lane];
    short8 Bf1 = wp1f[(wv * 2 + 1) * 64 + lane];
    const float av_s = a1s[wv * 16 + m];
    const float av_f = a1f[wv * 16 + m];
#pragma unroll
    for (int tt = 0; tt < 2; ++tt) {
        short8 A0 = xbs8[(tt * 16 + m) * 9 + quad];      // A[m][k=quad*8+j]
        short8 A1 = xbs8[(tt * 16 + m) * 9 + 4 + quad];  // A[m][k=32+quad*8+j]
        f32x4 accs = (f32x4){0.f, 0.f, 0.f, 0.f};
        f32x4 accf = (f32x4){0.f, 0.f, 0.f, 0.f};
        accs = __builtin_amdgcn_mfma_f32_16x16x32_bf16(A0, Bs0, accs, 0, 0, 0);
        accs = __builtin_amdgcn_mfma_f32_16x16x32_bf16(A1, Bs1, accs, 0, 0, 0);
        accf = __builtin_amdgcn_mfma_f32_16x16x32_bf16(A0, Bf0, accf, 0, 0, 0);
        accf = __builtin_amdgcn_mfma_f32_16x16x32_bf16(A1, Bf1, accf, 0, 0, 0);
#pragma unroll
        for (int reg = 0; reg < 4; reg++) {
            const int row = n0 * 4 + tt * 16 + quad * 4 + reg;
            h1_s[(long)row * 64 + wv * 16 + m] = f2bf(accs[reg]);
            h1_f[(long)row * 64 + wv * 16 + m] = f2bf(accf[reg]);
            float pS = accs[reg] * av_s;
            float pF = accf[reg] * av_f;
#pragma unroll
            for (int off = 1; off < 16; off <<= 1) {
                pS += __shfl_xor(pS, off, 64);
                pF += __shfl_xor(pF, off, 64);
            }
            if (m == 0) {
                psumS[wv][tt][quad * 4 + reg] = pS;  // partial over channels wv*16..+15
                psumF[wv][tt][quad * 4 + reg] = pF;
            }
        }
    }
    __syncthreads();
    if (threadIdx.x < 32) {
        const int r = threadIdx.x & 15, tt = threadIdx.x >> 4;
        float sS = (psumS[0][tt][r] + psumS[1][tt][r]) + (psumS[2][tt][r] + psumS[3][tt][r]);
        float sF = (psumF[0][tt][r] + psumF[1][tt][r]) + (psumF[2][tt][r] + psumF[3][tt][r]);
        float ls = (sS > 0.f) ? sS : NEG_SLOPE * sS;   // LeakyReLU folded in
        float lf = (sF > 0.f) ? sF : NEG_SLOPE * sF;
        esc1_s[n0 * 4 + tt * 16 + r] = __expf(ls);
        esc1_f[n0 * 4 + tt * 16 + r] = __expf(lf);
    }
}

// ---------------- dispatch 4: aggregate1 (writes final output) ----------------

__global__ __launch_bounds__(256) void a1_kernel(
    const float4* __restrict__ x4,
    const ushort4* __restrict__ hs4, const float* __restrict__ escs,
    const int* __restrict__ cnts, const int* __restrict__ cols,
    const ushort4* __restrict__ hf4, const float* __restrict__ escf,
    const int* __restrict__ cntf, const int* __restrict__ colf,
    const float4* __restrict__ g4, const float4* __restrict__ b4,
    float4* __restrict__ out4) {
    const int wv = threadIdx.x >> 6;
    const int lane = threadIdx.x & 63;
    const int t = lane >> 4;
    const int ci = lane & 15;
    const int nA = blockIdx.x * 8 + wv * 2, nB = nA + 1;
    float4 oA, oB;
    aggregate_pair(nA, nB, lane, t, x4, hs4, escs, cnts, cols,
                   hf4, escf, cntf, colf, g4[ci], b4[ci], oA, oB);
    out4[(long)nA * 64 + lane] = oA;
    out4[(long)nB * 64 + lane] = oB;
}

// ---------------- launch ----------------

extern "C" void kernel_launch(void* const* d_in, const int* in_sizes, int n_in,
                              void* d_out, int out_size, void* d_ws, size_t ws_size,
                              hipStream_t stream) {
    const float* pred = (const float*)d_in[0];
    const int* ei_s = (const int*)d_in[1];
    const int* ei_f = (const int*)d_in[2];
    const float* W0s = (const float*)d_in[3];
    const float* a0s = (const float*)d_in[4];
    const float* W0f = (const float*)d_in[5];
    const float* a0f = (const float*)d_in[6];
    const float* g0  = (const float*)d_in[7];
    const float* b0  = (const float*)d_in[8];
    const float* W1s = (const float*)d_in[9];
    const float* a1s = (const float*)d_in[10];
    const float* W1f = (const float*)d_in[11];
    const float* a1f = (const float*)d_in[12];
    const float* g1  = (const float*)d_in[13];
    const float* b1  = (const float*)d_in[14];
    const int E = in_sizes[1] / 2;  // 262144

    // workspace bump allocator (~68 MB)
    char* ws = (char*)d_ws;
    auto alloc = [&](size_t bytes) {
        char* p = ws;
        ws += (bytes + 255) & ~(size_t)255;
        return p;
    };
    int* cnt2 = (int*)alloc((size_t)2 * NN * sizeof(int));
    int* col2 = (int*)alloc((size_t)2 * NN * CAP * sizeof(int));
    short8* wpack = (short8*)alloc((size_t)4 * 512 * sizeof(short8));
    unsigned short* h0_s = (unsigned short*)alloc((size_t)NT * HH * sizeof(unsigned short));
    unsigned short* h0_f = (unsigned short*)alloc((size_t)NT * HH * sizeof(unsigned short));
    unsigned short* h1_s = (unsigned short*)alloc((size_t)NT * HH * sizeof(unsigned short));
    unsigned short* h1_f = (unsigned short*)alloc((size_t)NT * HH * sizeof(unsigned short));
    float* esc0_s = (float*)alloc((size_t)NT * sizeof(float));
    float* esc0_f = (float*)alloc((size_t)NT * sizeof(float));
    float* esc1_s = (float*)alloc((size_t)NT * sizeof(float));
    float* esc1_f = (float*)alloc((size_t)NT * sizeof(float));
    float* x_mid = (float*)alloc((size_t)NT * HH * sizeof(float));

    const int* cnt_s = cnt2;
    const int* cnt_f = cnt2 + NN;
    const int* col_s = col2;
    const int* col_f = col2 + (size_t)NN * CAP;

    const int SB = (2 * E + 255) / 256;  // scatter blocks

    // 1) zero counters + pack W fragments
    prep_kernel<<<136, 256, 0, stream>>>(W0s, W0f, W1s, W1f, wpack, cnt2);

    // 2) scatter || transform0
    st0_kernel<<<512 + SB, 256, 0, stream>>>(
        ei_s, ei_f, E, cnt2, col2,
        (const float4*)pred, wpack, a0s, a0f,
        h0_s, esc0_s, h0_f, esc0_f);

    // 3) aggregate0 + transform1 (paired waves, 8 nodes/block)
    a0t1_kernel<<<NN / 8, 256, 0, stream>>>(
        (const float4*)pred,
        (const ushort4*)h0_s, esc0_s, cnt_s, col_s,
        (const ushort4*)h0_f, esc0_f, cnt_f, col_f,
        (const float4*)g0, (const float4*)b0,
        (float4*)x_mid,
        wpack + 1024, wpack + 1536, a1s, a1f,
        h1_s, esc1_s, h1_f, esc1_f);

    // 4) aggregate1 -> output (paired waves)
    a1_kernel<<<NN / 8, 256, 0, stream>>>(
        (const float4*)x_mid,
        (const ushort4*)h1_s, esc1_s, cnt_s, col_s,
        (const ushort4*)h1_f, esc1_f, cnt_f, col_f,
        (const float4*)g1, (const float4*)b1, (float4*)d_out);
}